// Round 21
// baseline (14553.256 us; speedup 1.0000x reference)
//
#include <hip/hip_runtime.h>
#include <cstdint>
#include <cstddef>

#define T_LEN 2048
#define BATCH 128

typedef float v2f __attribute__((ext_vector_type(2)));

__device__ __forceinline__ float sigm(float x) {
  return __builtin_amdgcn_rcpf(1.0f + exp2f(-1.4426950408889634f * x));
}
__device__ __forceinline__ float tanh_fast(float x) {
  return 1.0f - 2.0f * __builtin_amdgcn_rcpf(1.0f + exp2f(2.8853900817779268f * x));
}

// lgkm-only fence + raw barrier: LDS writes visible across waves; global loads
// and h-stores stay in flight across the barrier.
#define BAR()                                              \
  do {                                                     \
    asm volatile("s_waitcnt lgkmcnt(0)" ::: "memory");     \
    __builtin_amdgcn_s_barrier();                          \
    asm volatile("" ::: "memory");                         \
  } while (0)

// ---------------- proj: in0[t*B+b, j] = relu(x[b,t,:] . w_proj[j,:] + b_proj[j])
__global__ __launch_bounds__(256) void proj_kernel(
    const float* __restrict__ x, const float* __restrict__ w_proj,
    const float* __restrict__ b_proj, float* __restrict__ in0) {
  int R = blockIdx.x * 4 + (threadIdx.x >> 6);  // R = t*BATCH + b
  int j = threadIdx.x & 63;
  int t = R >> 7;
  int b = R & 127;
  const float* xr = x + ((size_t)b * T_LEN + t) * 32;
  const float* wr = w_proj + j * 32;
  float a = b_proj[j];
#pragma unroll
  for (int k = 0; k < 32; ++k) a = fmaf(xr[k], wr[k], a);
  in0[(size_t)R * 64 + j] = fmaxf(a, 0.f);
}

// ================= SOLO-CONSUMER FUSED LSTM LAYER =================
// Block = (b, dir), 320 threads = 5 waves.
// R21 fix vs R20 (single variable): amdgpu_waves_per_eu(1, 1) — R20's "(1)"
// set only the MIN, the allocator kept its 128-VGPR occupancy target and
// spilled both roles' weight arrays (WRITE_SIZE 1.7 GB/dispatch = scratch).
// (1,1) forces 1 wave/EU -> 512-VGPR budget; consumer ~212, producer ~170.
// wave 0 (consumer): FULL recurrent dot, ZERO per-step barriers/exchanges.
//   Gates i,f weights in VGPR (64 v2f pk pairs); gates g,o in LDS with the
//   R11-verified XOR slot swizzle (h-independent reads, prefetched);
//   h broadcast via hcb write + uniform b128 reads. Barrier every 8 steps.
// waves 1-4 (producers): gate-split input GEMM (full K, bias folded) into a
//   2-deep 8-step pre ring; x chunks staged via 4-buf ring.
template <int DIN>
__global__ __attribute__((amdgpu_flat_work_group_size(320, 320),
                          amdgpu_waves_per_eu(1, 1)))
void lstm_solo(const float* __restrict__ in,    // [T*B][DIN]
               float* __restrict__ out,         // [T*B][128]
               const float* __restrict__ w_ih,  // [2,256,DIN]
               const float* __restrict__ w_hh,  // [2,256,64]
               const float* __restrict__ bias)  // [2,256]
{
  constexpr int NF4C = 8 * DIN / 4;  // float4s per 8-step x chunk (256/128)
  constexpr int NCH = T_LEN / 8;     // 8-step chunks

  const int tid = threadIdx.x;
  const int dir = blockIdx.x & 1;
  const int b = blockIdx.x >> 1;
  const int wv = tid >> 6;  // 0 = consumer, 1..4 = producer gate wv-1
  const int l = tid & 63;

  __shared__ float xc[4][8][DIN];     // x chunk ring
  __shared__ float pre2[2][8][256];   // complete pre (bias folded), 2-deep
  __shared__ float wg[64][64];        // gate-g w_hh rows, XOR slot swizzle
  __shared__ float wo[64][64];        // gate-o w_hh rows, XOR slot swizzle
  __shared__ float hcb[64];           // consumer h broadcast row

  // ---- cooperative init: x chunks 0,1 + swizzled wg/wo
  {
    int total = 2 * NF4C;
#pragma unroll
    for (int q = 0; q < (2 * 256 + 319) / 320; ++q) {
      int idx = tid + 320 * q;
      if (idx < total) {
        int ch = idx / NF4C, r = idx % NF4C;
        int sl = r / (DIN / 4), col = r % (DIN / 4);
        int sg = ch * 8 + sl;
        long t = dir ? (T_LEN - 1 - sg) : sg;
        *(float4*)&xc[ch][sl][col * 4] =
            *(const float4*)(in + ((size_t)t * BATCH + b) * DIN + col * 4);
      }
    }
    // wg/wo: row r slot s (16 slots of 16B) stored at phys slot s^(r&15)
#pragma unroll
    for (int q = 0; q < 7; ++q) {
      int idx = tid + 320 * q;
      if (idx < 2048) {
        int arr = idx >> 10, rem = idx & 1023;
        int r = rem >> 4, s = rem & 15;
        float4 v = *(const float4*)(w_hh +
            (size_t)(dir * 256 + 128 + arr * 64 + r) * 64 + 4 * s);
        float* dst = arr ? &wo[r][0] : &wg[r][0];
        *(float4*)&dst[((s ^ (r & 15)) * 4)] = v;
      }
    }
  }
  if (wv == 0) hcb[l] = 0.f;  // h_0 = 0
  __syncthreads();

  if (wv >= 1) {
    // ================= producer: gate g = wv-1, full K =================
    const int g = wv - 1;
    float4 wihr[DIN / 4];
    {
      const float4* p =
          (const float4*)(w_ih + (size_t)(dir * 256 + g * 64 + l) * DIN);
#pragma unroll
      for (int k = 0; k < DIN / 4; ++k) wihr[k] = p[k];
    }
    const v2f* wp = (const v2f*)wihr;  // DIN/2 k-pairs
    const float bz = bias[dir * 256 + g * 64 + l];
    const int ptid = tid - 64;  // 0..255

    auto pcompute = [&](int xb, int pb) {
#pragma unroll
      for (int j = 0; j < 8; ++j) {
        const float* xrow = &xc[xb][j][0];
        v2f a0 = (v2f){bz, 0.f}, a1 = (v2f){0.f, 0.f};
        v2f a2 = (v2f){0.f, 0.f}, a3 = (v2f){0.f, 0.f};
#pragma unroll
        for (int kc = 0; kc < DIN / 16; ++kc) {
          float4 xq[4];
#pragma unroll
          for (int q = 0; q < 4; ++q)
            xq[q] = *(const float4*)&xrow[kc * 16 + 4 * q];  // uniform
          const v2f* xp = (const v2f*)xq;
          a0 = __builtin_elementwise_fma(xp[0], wp[kc * 8 + 0], a0);
          a1 = __builtin_elementwise_fma(xp[1], wp[kc * 8 + 1], a1);
          a2 = __builtin_elementwise_fma(xp[2], wp[kc * 8 + 2], a2);
          a3 = __builtin_elementwise_fma(xp[3], wp[kc * 8 + 3], a3);
          a0 = __builtin_elementwise_fma(xp[4], wp[kc * 8 + 4], a0);
          a1 = __builtin_elementwise_fma(xp[5], wp[kc * 8 + 5], a1);
          a2 = __builtin_elementwise_fma(xp[6], wp[kc * 8 + 6], a2);
          a3 = __builtin_elementwise_fma(xp[7], wp[kc * 8 + 7], a3);
        }
        pre2[pb][j][g * 64 + l] =
            ((a0.x + a0.y) + (a1.x + a1.y)) + ((a2.x + a2.y) + (a3.x + a3.y));
      }
    };

    pcompute(0, 0);  // prologue: chunk 0
    __syncthreads();

    float4 stg;
    const int scol = (ptid % (DIN / 4)) * 4;
    const int srow = ptid / (DIN / 4);
#pragma unroll 2
    for (int cc = 0; cc < NCH; ++cc) {
      // stage ISSUE chunk cc+2
      if (cc + 2 < NCH && ptid < NF4C) {
        int sg = (cc + 2) * 8 + srow;
        long t = dir ? (T_LEN - 1 - sg) : sg;
        stg = *(const float4*)(in + ((size_t)t * BATCH + b) * DIN + scol);
      }
      // compute pre chunk cc+1
      if (cc + 1 < NCH) pcompute((cc + 1) & 3, (cc + 1) & 1);
      // stage WRITE chunk cc+2 (latency covered by pcompute)
      if (cc + 2 < NCH && ptid < NF4C)
        *(float4*)&xc[(cc + 2) & 3][srow][scol] = stg;
      BAR();
    }
  } else {
    // ================= consumer (wave 0, full dot, no per-step sync) =====
    float4 wifr[32];  // gate i rows l (16 f4) + gate f rows 64+l (16 f4)
    {
      const float4* qi = (const float4*)(w_hh + (size_t)(dir * 256 + l) * 64);
      const float4* qf =
          (const float4*)(w_hh + (size_t)(dir * 256 + 64 + l) * 64);
#pragma unroll
      for (int k = 0; k < 16; ++k) {
        wifr[k] = qi[k];
        wifr[16 + k] = qf[k];
      }
    }
    const v2f* wif2 = (const v2f*)wifr;  // [0..31]=i pairs, [32..63]=f pairs
    const int swz = l & 15;

    float* outp =
        out + ((size_t)(dir ? (T_LEN - 1) : 0) * BATCH + b) * 128 + dir * 64 + l;
    const ptrdiff_t ostride =
        dir ? -(ptrdiff_t)(BATCH * 128) : (ptrdiff_t)(BATCH * 128);

    __syncthreads();  // matches producer prologue sync

    float h = 0.f, c = 0.f;
#pragma unroll 2
    for (int cc = 0; cc < NCH; ++cc) {
      const int cb = cc & 1;
#pragma unroll
      for (int s = 0; s < 8; ++s) {
        // complete pre (bias folded by producers) — h-independent
        float pi = pre2[cb][s][l];
        float pf = pre2[cb][s][64 + l];
        float pg = pre2[cb][s][128 + l];
        float po = pre2[cb][s][192 + l];

        v2f ai0 = (v2f){0.f, 0.f}, ai1 = (v2f){0.f, 0.f};
        v2f af0 = (v2f){0.f, 0.f}, af1 = (v2f){0.f, 0.f};
        v2f ag0 = (v2f){0.f, 0.f}, ag1 = (v2f){0.f, 0.f};
        v2f ao0 = (v2f){0.f, 0.f}, ao1 = (v2f){0.f, 0.f};
#pragma unroll
        for (int kc = 0; kc < 4; ++kc) {
          float4 hq[4], wgv[4], wov[4];
#pragma unroll
          for (int q = 0; q < 4; ++q)
            hq[q] = *(const float4*)&hcb[kc * 16 + 4 * q];  // uniform
#pragma unroll
          for (int q = 0; q < 4; ++q)
            wgv[q] = *(const float4*)&wg[l][((kc * 4 + q) ^ swz) * 4];
#pragma unroll
          for (int q = 0; q < 4; ++q)
            wov[q] = *(const float4*)&wo[l][((kc * 4 + q) ^ swz) * 4];
          const v2f* hp = (const v2f*)hq;
          const v2f* wgp = (const v2f*)wgv;
          const v2f* wop = (const v2f*)wov;
#pragma unroll
          for (int p = 0; p < 8; ++p) {
            v2f h2 = hp[p];
            if (p & 1) {
              ai1 = __builtin_elementwise_fma(h2, wif2[kc * 8 + p], ai1);
              af1 = __builtin_elementwise_fma(h2, wif2[32 + kc * 8 + p], af1);
              ag1 = __builtin_elementwise_fma(h2, wgp[p], ag1);
              ao1 = __builtin_elementwise_fma(h2, wop[p], ao1);
            } else {
              ai0 = __builtin_elementwise_fma(h2, wif2[kc * 8 + p], ai0);
              af0 = __builtin_elementwise_fma(h2, wif2[32 + kc * 8 + p], af0);
              ag0 = __builtin_elementwise_fma(h2, wgp[p], ag0);
              ao0 = __builtin_elementwise_fma(h2, wop[p], ao0);
            }
          }
        }
        v2f ai = ai0 + ai1, af = af0 + af1, ag = ag0 + ag1, ao = ao0 + ao1;
        float zi = pi + (ai.x + ai.y);
        float zf = pf + (af.x + af.y);
        float zg = pg + (ag.x + ag.y);
        float zo = po + (ao.x + ao.y);
        float ig = sigm(zi), fg = sigm(zf), gg = tanh_fast(zg), og = sigm(zo);
        c = fmaf(fg, c, ig * gg);
        h = og * tanh_fast(c);
        hcb[l] = h;  // same-wave program order: next step's reads see it
        *outp = h;   // stays in flight (lgkm-only barriers)
        outp += ostride;
      }
      BAR();
    }
  }
}

// ---------------- attention: scores + softmax + pooled, one block per batch row
__global__ __launch_bounds__(256) void attn_kernel(
    const float* __restrict__ hs, const float* __restrict__ w_attn,
    float* __restrict__ pooled) {
  const int b = blockIdx.x, tid = threadIdx.x;
  __shared__ float wa[128];
  __shared__ float sc[T_LEN];
  __shared__ float red[256];
  if (tid < 128) wa[tid] = w_attn[tid];
  __syncthreads();

  float lmax = -3.4e38f;
#pragma unroll
  for (int i = 0; i < T_LEN / 256; ++i) {
    int t = tid + 256 * i;
    const float4* r4 = (const float4*)(hs + ((size_t)t * BATCH + b) * 128);
    float s = 0.f;
#pragma unroll
    for (int k = 0; k < 32; ++k) {
      float4 v = r4[k];
      s += v.x * wa[4 * k] + v.y * wa[4 * k + 1] + v.z * wa[4 * k + 2] + v.w * wa[4 * k + 3];
    }
    sc[t] = s;
    lmax = fmaxf(lmax, s);
  }
  red[tid] = lmax;
  __syncthreads();
  for (int off = 128; off > 0; off >>= 1) {
    if (tid < off) red[tid] = fmaxf(red[tid], red[tid + off]);
    __syncthreads();
  }
  float m = red[0];
  __syncthreads();

  float lsum = 0.f;
#pragma unroll
  for (int i = 0; i < T_LEN / 256; ++i) {
    int t = tid + 256 * i;
    float e = exp2f((sc[t] - m) * 1.4426950408889634f);
    sc[t] = e;
    lsum += e;
  }
  red[tid] = lsum;
  __syncthreads();
  for (int off = 128; off > 0; off >>= 1) {
    if (tid < off) red[tid] += red[tid + off];
    __syncthreads();
  }
  float inv = __builtin_amdgcn_rcpf(red[0]);

  if (tid < 128) {
    float a0 = 0.f, a1 = 0.f, a2 = 0.f, a3 = 0.f;
    for (int t = 0; t < T_LEN; t += 4) {
      a0 = fmaf(sc[t], hs[((size_t)t * BATCH + b) * 128 + tid], a0);
      a1 = fmaf(sc[t + 1], hs[((size_t)(t + 1) * BATCH + b) * 128 + tid], a1);
      a2 = fmaf(sc[t + 2], hs[((size_t)(t + 2) * BATCH + b) * 128 + tid], a2);
      a3 = fmaf(sc[t + 3], hs[((size_t)(t + 3) * BATCH + b) * 128 + tid], a3);
    }
    pooled[b * 128 + tid] = ((a0 + a1) + (a2 + a3)) * inv;
  }
}

// ---------------- head: BN1 -> fc1 -> relu -> fc2 -> elu -> BN2 -> fc3
__global__ __launch_bounds__(128) void head_kernel(
    const float* __restrict__ pooled,
    const float* g1, const float* be1, const float* m1, const float* v1,
    const float* w1, const float* b1, const float* w2, const float* b2,
    const float* g2, const float* be2, const float* m2, const float* v2,
    const float* w3, const float* b3, float* __restrict__ out) {
  const int b = blockIdx.x, tid = threadIdx.x;
  __shared__ float xb[128], y1[128], y2[64];
  xb[tid] = (pooled[b * 128 + tid] - m1[tid]) * rsqrtf(v1[tid] + 1e-5f) * g1[tid] + be1[tid];
  __syncthreads();
  float a = b1[tid];
#pragma unroll 8
  for (int k = 0; k < 128; ++k) a = fmaf(xb[k], w1[tid * 128 + k], a);
  y1[tid] = fmaxf(a, 0.f);
  __syncthreads();
  if (tid < 64) {
    float a2 = b2[tid];
#pragma unroll 8
    for (int k = 0; k < 128; ++k) a2 = fmaf(y1[k], w2[tid * 128 + k], a2);
    if (a2 < 0.f) a2 = exp2f(a2 * 1.4426950408889634f) - 1.0f;  // elu
    y2[tid] = (a2 - m2[tid]) * rsqrtf(v2[tid] + 1e-5f) * g2[tid] + be2[tid];
  }
  __syncthreads();
  if (tid < 3) {
    float a3 = b3[tid];
#pragma unroll
    for (int k = 0; k < 64; ++k) a3 = fmaf(y2[k], w3[tid * 64 + k], a3);
    out[b * 3 + tid] = a3;
  }
}

extern "C" void kernel_launch(void* const* d_in, const int* in_sizes, int n_in,
                              void* d_out, int out_size, void* d_ws, size_t ws_size,
                              hipStream_t stream) {
  const float* x      = (const float*)d_in[0];
  const float* w_proj = (const float*)d_in[1];
  const float* b_proj = (const float*)d_in[2];
  const float* w_ih_l0 = (const float*)d_in[3];
  const float* w_hh_l0 = (const float*)d_in[4];
  const float* b_l0    = (const float*)d_in[5];
  const float* w_ih_r  = (const float*)d_in[6];  // [3,2,256,128]
  const float* w_hh_r  = (const float*)d_in[7];  // [3,2,256,64]
  const float* b_r     = (const float*)d_in[8];  // [3,2,256]
  const float* w_attn  = (const float*)d_in[9];
  const float* g1  = (const float*)d_in[11];
  const float* be1 = (const float*)d_in[12];
  const float* m1  = (const float*)d_in[13];
  const float* v1  = (const float*)d_in[14];
  const float* w1  = (const float*)d_in[15];
  const float* b1  = (const float*)d_in[16];
  const float* w2  = (const float*)d_in[17];
  const float* b2  = (const float*)d_in[18];
  const float* g2  = (const float*)d_in[19];
  const float* be2 = (const float*)d_in[20];
  const float* m2  = (const float*)d_in[21];
  const float* v2  = (const float*)d_in[22];
  const float* w3  = (const float*)d_in[23];
  const float* b3  = (const float*)d_in[24];
  float* out = (float*)d_out;

  // ws layout: bufA [T,B,128] | bufB [T,B,128]  (in0 and pooled overlay dead regions)
  const size_t BUF_FLOATS = (size_t)T_LEN * BATCH * 128;
  float* bufA = (float*)d_ws;
  float* bufB = bufA + BUF_FLOATS;
  float* in0 = bufB;     // [T,B,64]; dead once layer1 writes bufB
  float* pooled = bufA;  // dead region after last layer reads bufA

  proj_kernel<<<T_LEN * BATCH / 4, 256, 0, stream>>>(x, w_proj, b_proj, in0);
  lstm_solo<64><<<256, 320, 0, stream>>>(in0, bufA, w_ih_l0, w_hh_l0, b_l0);
  lstm_solo<128><<<256, 320, 0, stream>>>(bufA, bufB, w_ih_r, w_hh_r, b_r);
  lstm_solo<128><<<256, 320, 0, stream>>>(bufB, bufA, w_ih_r + 65536, w_hh_r + 32768, b_r + 512);
  lstm_solo<128><<<256, 320, 0, stream>>>(bufA, bufB, w_ih_r + 131072, w_hh_r + 65536, b_r + 1024);
  attn_kernel<<<BATCH, 256, 0, stream>>>(bufB, w_attn, pooled);
  head_kernel<<<BATCH, 128, 0, stream>>>(pooled, g1, be1, m1, v1, w1, b1, w2, b2,
                                         g2, be2, m2, v2, w3, b3, out);
}

// Round 23
// 8334.147 us; speedup vs baseline: 1.7462x; 1.7462x over previous
//
#include <hip/hip_runtime.h>
#include <cstdint>
#include <cstddef>

#define T_LEN 2048
#define BATCH 128

typedef float v2f __attribute__((ext_vector_type(2)));

__device__ __forceinline__ float sigm(float x) {
  return __builtin_amdgcn_rcpf(1.0f + exp2f(-1.4426950408889634f * x));
}
__device__ __forceinline__ float tanh_fast(float x) {
  return 1.0f - 2.0f * __builtin_amdgcn_rcpf(1.0f + exp2f(2.8853900817779268f * x));
}

// lgkm-only fence + raw barrier: LDS writes visible across waves; global loads
// and h-stores stay in flight across the barrier.
#define BAR()                                              \
  do {                                                     \
    asm volatile("s_waitcnt lgkmcnt(0)" ::: "memory");     \
    __builtin_amdgcn_s_barrier();                          \
    asm volatile("" ::: "memory");                         \
  } while (0)

// ---------------- proj: in0[t*B+b, j] = relu(x[b,t,:] . w_proj[j,:] + b_proj[j])
__global__ __launch_bounds__(256) void proj_kernel(
    const float* __restrict__ x, const float* __restrict__ w_proj,
    const float* __restrict__ b_proj, float* __restrict__ in0) {
  int R = blockIdx.x * 4 + (threadIdx.x >> 6);  // R = t*BATCH + b
  int j = threadIdx.x & 63;
  int t = R >> 7;
  int b = R & 127;
  const float* xr = x + ((size_t)b * T_LEN + t) * 32;
  const float* wr = w_proj + j * 32;
  float a = b_proj[j];
#pragma unroll
  for (int k = 0; k < 32; ++k) a = fmaf(xr[k], wr[k], a);
  in0[(size_t)R * 64 + j] = fmaxf(a, 0.f);
}

// ================= SOLO-CONSUMER FUSED LSTM LAYER (4-wave legal) =============
// R23 fix vs R22 (one line): restore the `ptid < NF4C` guard on the PRIMARY
// x-staging load/write. For DIN=64 (NF4C=128) wave-3 threads (ptid 128..191)
// computed srow0=8..11 and wrote past the 8-row chunk into the next ring
// slot -> corrupted layer-0 x inputs -> absmax 5.5e-4. DIN=128 unaffected.
// Structure (R22): 256 thr = 4 waves, waves_per_eu(1,1) -> 512-VGPR budget.
// wave 0 (consumer): FULL recurrent dot, no per-step barrier. Gates i,f
//   weights in VGPR (64 v2f pk pairs); gates g,o in LDS (XOR slot swizzle,
//   h-independent prefetch); h via hcb + uniform b128 reads.
// waves 1-3 (producers): K-slices 48/48/32 (24/24/16 for DIN=64), each
//   computes all 4 gates over its slice into pre2[2][8][3][256]; bias in
//   slice 0; x chunks staged by producer threads (issue early / write late).
template <int DIN, int LO, int HI>
__device__ __forceinline__ void solo_producer(
    const float* __restrict__ in, const float* __restrict__ w_ih,
    const float* __restrict__ bias, int dir, int b, int l, int ptid, int ps,
    float (&xc)[4][8][DIN], float (&pre2)[2][8][3][256]) {
  constexpr int NW = HI - LO;        // slice width (48/48/32 or 24/24/16)
  constexpr int NF4 = NW / 4;
  constexpr int NF4C = 8 * DIN / 4;  // float4s per 8-step x chunk
  constexpr int NCH = T_LEN / 8;

  float4 wihr[4 * NF4];  // 4 gate rows x NW cols
#pragma unroll
  for (int m = 0; m < 4; ++m) {
    const float4* p =
        (const float4*)(w_ih + (size_t)(dir * 256 + m * 64 + l) * DIN + LO);
#pragma unroll
    for (int k = 0; k < NF4; ++k) wihr[m * NF4 + k] = p[k];
  }
  const v2f* wp = (const v2f*)wihr;  // [4][NW/2] k-pairs
  float bz0 = 0.f, bz1 = 0.f, bz2 = 0.f, bz3 = 0.f;
  if (ps == 0) {
    bz0 = bias[dir * 256 + l];
    bz1 = bias[dir * 256 + 64 + l];
    bz2 = bias[dir * 256 + 128 + l];
    bz3 = bias[dir * 256 + 192 + l];
  }

  auto pcompute = [&](int xb, int pb) {
#pragma unroll
    for (int j = 0; j < 8; ++j) {
      const float* xrow = &xc[xb][j][LO];
      float4 xq[NF4];
#pragma unroll
      for (int q = 0; q < NF4; ++q)
        xq[q] = *(const float4*)&xrow[4 * q];  // uniform b128 broadcast
      const v2f* xp = (const v2f*)xq;
      v2f a0 = (v2f){bz0, 0.f}, a1 = (v2f){bz1, 0.f};
      v2f a2 = (v2f){bz2, 0.f}, a3 = (v2f){bz3, 0.f};
#pragma unroll
      for (int p = 0; p < NW / 2; ++p) {
        v2f x2 = xp[p];
        a0 = __builtin_elementwise_fma(x2, wp[0 * (NW / 2) + p], a0);
        a1 = __builtin_elementwise_fma(x2, wp[1 * (NW / 2) + p], a1);
        a2 = __builtin_elementwise_fma(x2, wp[2 * (NW / 2) + p], a2);
        a3 = __builtin_elementwise_fma(x2, wp[3 * (NW / 2) + p], a3);
      }
      pre2[pb][j][ps][l] = a0.x + a0.y;
      pre2[pb][j][ps][64 + l] = a1.x + a1.y;
      pre2[pb][j][ps][128 + l] = a2.x + a2.y;
      pre2[pb][j][ps][192 + l] = a3.x + a3.y;
    }
  };

  pcompute(0, 0);  // prologue: chunk 0
  __syncthreads();

  float4 stg[2];
  const int scol0 = (ptid % (DIN / 4)) * 4;
  const int srow0 = ptid / (DIN / 4);
  const int idx1 = ptid + 192;
  const int scol1 = (idx1 % (DIN / 4)) * 4;
  const int srow1 = idx1 / (DIN / 4);
#pragma unroll 2
  for (int cc = 0; cc < NCH; ++cc) {
    // stage ISSUE chunk cc+2 (BOTH slots guarded vs NF4C — R23 fix)
    if (cc + 2 < NCH) {
      if (ptid < NF4C) {
        int sg = (cc + 2) * 8 + srow0;
        long t = dir ? (T_LEN - 1 - sg) : sg;
        stg[0] = *(const float4*)(in + ((size_t)t * BATCH + b) * DIN + scol0);
      }
      if (idx1 < NF4C) {
        int sg = (cc + 2) * 8 + srow1;
        long t = dir ? (T_LEN - 1 - sg) : sg;
        stg[1] = *(const float4*)(in + ((size_t)t * BATCH + b) * DIN + scol1);
      }
    }
    // compute pre chunk cc+1
    if (cc + 1 < NCH) pcompute((cc + 1) & 3, (cc + 1) & 1);
    // stage WRITE chunk cc+2 (latency covered by pcompute)
    if (cc + 2 < NCH) {
      if (ptid < NF4C) *(float4*)&xc[(cc + 2) & 3][srow0][scol0] = stg[0];
      if (idx1 < NF4C) *(float4*)&xc[(cc + 2) & 3][srow1][scol1] = stg[1];
    }
    BAR();
  }
}

template <int DIN>
__global__ __attribute__((amdgpu_flat_work_group_size(256, 256),
                          amdgpu_waves_per_eu(1, 1)))
void lstm_solo(const float* __restrict__ in,    // [T*B][DIN]
               float* __restrict__ out,         // [T*B][128]
               const float* __restrict__ w_ih,  // [2,256,DIN]
               const float* __restrict__ w_hh,  // [2,256,64]
               const float* __restrict__ bias)  // [2,256]
{
  constexpr int NF4C = 8 * DIN / 4;
  constexpr int NCH = T_LEN / 8;
  constexpr int L1 = (DIN == 128) ? 48 : 24;
  constexpr int L2 = (DIN == 128) ? 96 : 48;

  const int tid = threadIdx.x;
  const int dir = blockIdx.x & 1;
  const int b = blockIdx.x >> 1;
  const int wv = tid >> 6;  // 0 = consumer, 1..3 = producer slice wv-1
  const int l = tid & 63;

  __shared__ float xc[4][8][DIN];      // x chunk ring
  __shared__ float pre2[2][8][3][256]; // pre partial slices, 2-deep ring
  __shared__ float wg[64][64];         // gate-g w_hh rows, XOR slot swizzle
  __shared__ float wo[64][64];         // gate-o w_hh rows, XOR slot swizzle
  __shared__ float hcb[64];            // consumer h broadcast row

  // ---- cooperative init: x chunks 0,1 + swizzled wg/wo
  {
#pragma unroll
    for (int q = 0; q < 2; ++q) {
      int idx = tid + 256 * q;
      if (idx < 2 * NF4C) {
        int ch = idx / NF4C, r = idx % NF4C;
        int sl = r / (DIN / 4), col = r % (DIN / 4);
        int sg = ch * 8 + sl;
        long t = dir ? (T_LEN - 1 - sg) : sg;
        *(float4*)&xc[ch][sl][col * 4] =
            *(const float4*)(in + ((size_t)t * BATCH + b) * DIN + col * 4);
      }
    }
    // wg/wo: row r slot s (16 slots of 16B) stored at phys slot s^(r&15)
#pragma unroll
    for (int q = 0; q < 8; ++q) {
      int idx = tid + 256 * q;
      int arr = idx >> 10, rem = idx & 1023;
      int r = rem >> 4, s = rem & 15;
      float4 v = *(const float4*)(w_hh +
          (size_t)(dir * 256 + 128 + arr * 64 + r) * 64 + 4 * s);
      float* dst = arr ? &wo[r][0] : &wg[r][0];
      *(float4*)&dst[((s ^ (r & 15)) * 4)] = v;
    }
  }
  if (wv == 0) hcb[l] = 0.f;  // h_0 = 0
  __syncthreads();

  if (wv == 1) {
    solo_producer<DIN, 0, L1>(in, w_ih, bias, dir, b, l, tid - 64, 0, xc, pre2);
  } else if (wv == 2) {
    solo_producer<DIN, L1, L2>(in, w_ih, bias, dir, b, l, tid - 64, 1, xc, pre2);
  } else if (wv == 3) {
    solo_producer<DIN, L2, DIN>(in, w_ih, bias, dir, b, l, tid - 64, 2, xc, pre2);
  } else {
    // ================= consumer (wave 0, full dot, no per-step sync) =====
    float4 wifr[32];  // gate i rows l (16 f4) + gate f rows 64+l (16 f4)
    {
      const float4* qi = (const float4*)(w_hh + (size_t)(dir * 256 + l) * 64);
      const float4* qf =
          (const float4*)(w_hh + (size_t)(dir * 256 + 64 + l) * 64);
#pragma unroll
      for (int k = 0; k < 16; ++k) {
        wifr[k] = qi[k];
        wifr[16 + k] = qf[k];
      }
    }
    const v2f* wif2 = (const v2f*)wifr;  // [0..31]=i pairs, [32..63]=f pairs
    const int swz = l & 15;

    float* outp =
        out + ((size_t)(dir ? (T_LEN - 1) : 0) * BATCH + b) * 128 + dir * 64 + l;
    const ptrdiff_t ostride =
        dir ? -(ptrdiff_t)(BATCH * 128) : (ptrdiff_t)(BATCH * 128);

    __syncthreads();  // matches producer prologue sync

    float h = 0.f, c = 0.f;
#pragma unroll 2
    for (int cc = 0; cc < NCH; ++cc) {
      const int cb = cc & 1;
#pragma unroll
      for (int s = 0; s < 8; ++s) {
        // pre = sum of 3 K-slice partials (bias folded; h-independent)
        const float* pp = &pre2[cb][s][0][0];
        float pi = (pp[l] + pp[256 + l]) + pp[512 + l];
        float pf = (pp[64 + l] + pp[320 + l]) + pp[576 + l];
        float pg = (pp[128 + l] + pp[384 + l]) + pp[640 + l];
        float po = (pp[192 + l] + pp[448 + l]) + pp[704 + l];

        v2f ai0 = (v2f){0.f, 0.f}, ai1 = (v2f){0.f, 0.f};
        v2f af0 = (v2f){0.f, 0.f}, af1 = (v2f){0.f, 0.f};
        v2f ag0 = (v2f){0.f, 0.f}, ag1 = (v2f){0.f, 0.f};
        v2f ao0 = (v2f){0.f, 0.f}, ao1 = (v2f){0.f, 0.f};
#pragma unroll
        for (int kc = 0; kc < 4; ++kc) {
          float4 hq[4], wgv[4], wov[4];
#pragma unroll
          for (int q = 0; q < 4; ++q)
            hq[q] = *(const float4*)&hcb[kc * 16 + 4 * q];  // uniform
#pragma unroll
          for (int q = 0; q < 4; ++q)
            wgv[q] = *(const float4*)&wg[l][((kc * 4 + q) ^ swz) * 4];
#pragma unroll
          for (int q = 0; q < 4; ++q)
            wov[q] = *(const float4*)&wo[l][((kc * 4 + q) ^ swz) * 4];
          const v2f* hp = (const v2f*)hq;
          const v2f* wgp = (const v2f*)wgv;
          const v2f* wop = (const v2f*)wov;
#pragma unroll
          for (int p = 0; p < 8; ++p) {
            v2f h2 = hp[p];
            if (p & 1) {
              ai1 = __builtin_elementwise_fma(h2, wif2[kc * 8 + p], ai1);
              af1 = __builtin_elementwise_fma(h2, wif2[32 + kc * 8 + p], af1);
              ag1 = __builtin_elementwise_fma(h2, wgp[p], ag1);
              ao1 = __builtin_elementwise_fma(h2, wop[p], ao1);
            } else {
              ai0 = __builtin_elementwise_fma(h2, wif2[kc * 8 + p], ai0);
              af0 = __builtin_elementwise_fma(h2, wif2[32 + kc * 8 + p], af0);
              ag0 = __builtin_elementwise_fma(h2, wgp[p], ag0);
              ao0 = __builtin_elementwise_fma(h2, wop[p], ao0);
            }
          }
        }
        v2f ai = ai0 + ai1, af = af0 + af1, ag = ag0 + ag1, ao = ao0 + ao1;
        float zi = pi + (ai.x + ai.y);
        float zf = pf + (af.x + af.y);
        float zg = pg + (ag.x + ag.y);
        float zo = po + (ao.x + ao.y);
        float ig = sigm(zi), fg = sigm(zf), gg = tanh_fast(zg), og = sigm(zo);
        c = fmaf(fg, c, ig * gg);
        h = og * tanh_fast(c);
        hcb[l] = h;  // same-wave program order: next step's reads see it
        *outp = h;   // stays in flight (lgkm-only barriers)
        outp += ostride;
      }
      BAR();
    }
  }
}

// ---------------- attention: scores + softmax + pooled, one block per batch row
__global__ __launch_bounds__(256) void attn_kernel(
    const float* __restrict__ hs, const float* __restrict__ w_attn,
    float* __restrict__ pooled) {
  const int b = blockIdx.x, tid = threadIdx.x;
  __shared__ float wa[128];
  __shared__ float sc[T_LEN];
  __shared__ float red[256];
  if (tid < 128) wa[tid] = w_attn[tid];
  __syncthreads();

  float lmax = -3.4e38f;
#pragma unroll
  for (int i = 0; i < T_LEN / 256; ++i) {
    int t = tid + 256 * i;
    const float4* r4 = (const float4*)(hs + ((size_t)t * BATCH + b) * 128);
    float s = 0.f;
#pragma unroll
    for (int k = 0; k < 32; ++k) {
      float4 v = r4[k];
      s += v.x * wa[4 * k] + v.y * wa[4 * k + 1] + v.z * wa[4 * k + 2] + v.w * wa[4 * k + 3];
    }
    sc[t] = s;
    lmax = fmaxf(lmax, s);
  }
  red[tid] = lmax;
  __syncthreads();
  for (int off = 128; off > 0; off >>= 1) {
    if (tid < off) red[tid] = fmaxf(red[tid], red[tid + off]);
    __syncthreads();
  }
  float m = red[0];
  __syncthreads();

  float lsum = 0.f;
#pragma unroll
  for (int i = 0; i < T_LEN / 256; ++i) {
    int t = tid + 256 * i;
    float e = exp2f((sc[t] - m) * 1.4426950408889634f);
    sc[t] = e;
    lsum += e;
  }
  red[tid] = lsum;
  __syncthreads();
  for (int off = 128; off > 0; off >>= 1) {
    if (tid < off) red[tid] += red[tid + off];
    __syncthreads();
  }
  float inv = __builtin_amdgcn_rcpf(red[0]);

  if (tid < 128) {
    float a0 = 0.f, a1 = 0.f, a2 = 0.f, a3 = 0.f;
    for (int t = 0; t < T_LEN; t += 4) {
      a0 = fmaf(sc[t], hs[((size_t)t * BATCH + b) * 128 + tid], a0);
      a1 = fmaf(sc[t + 1], hs[((size_t)(t + 1) * BATCH + b) * 128 + tid], a1);
      a2 = fmaf(sc[t + 2], hs[((size_t)(t + 2) * BATCH + b) * 128 + tid], a2);
      a3 = fmaf(sc[t + 3], hs[((size_t)(t + 3) * BATCH + b) * 128 + tid], a3);
    }
    pooled[b * 128 + tid] = ((a0 + a1) + (a2 + a3)) * inv;
  }
}

// ---------------- head: BN1 -> fc1 -> relu -> fc2 -> elu -> BN2 -> fc3
__global__ __launch_bounds__(128) void head_kernel(
    const float* __restrict__ pooled,
    const float* g1, const float* be1, const float* m1, const float* v1,
    const float* w1, const float* b1, const float* w2, const float* b2,
    const float* g2, const float* be2, const float* m2, const float* v2,
    const float* w3, const float* b3, float* __restrict__ out) {
  const int b = blockIdx.x, tid = threadIdx.x;
  __shared__ float xb[128], y1[128], y2[64];
  xb[tid] = (pooled[b * 128 + tid] - m1[tid]) * rsqrtf(v1[tid] + 1e-5f) * g1[tid] + be1[tid];
  __syncthreads();
  float a = b1[tid];
#pragma unroll 8
  for (int k = 0; k < 128; ++k) a = fmaf(xb[k], w1[tid * 128 + k], a);
  y1[tid] = fmaxf(a, 0.f);
  __syncthreads();
  if (tid < 64) {
    float a2 = b2[tid];
#pragma unroll 8
    for (int k = 0; k < 128; ++k) a2 = fmaf(y1[k], w2[tid * 128 + k], a2);
    if (a2 < 0.f) a2 = exp2f(a2 * 1.4426950408889634f) - 1.0f;  // elu
    y2[tid] = (a2 - m2[tid]) * rsqrtf(v2[tid] + 1e-5f) * g2[tid] + be2[tid];
  }
  __syncthreads();
  if (tid < 3) {
    float a3 = b3[tid];
#pragma unroll
    for (int k = 0; k < 64; ++k) a3 = fmaf(y2[k], w3[tid * 64 + k], a3);
    out[b * 3 + tid] = a3;
  }
}

extern "C" void kernel_launch(void* const* d_in, const int* in_sizes, int n_in,
                              void* d_out, int out_size, void* d_ws, size_t ws_size,
                              hipStream_t stream) {
  const float* x      = (const float*)d_in[0];
  const float* w_proj = (const float*)d_in[1];
  const float* b_proj = (const float*)d_in[2];
  const float* w_ih_l0 = (const float*)d_in[3];
  const float* w_hh_l0 = (const float*)d_in[4];
  const float* b_l0    = (const float*)d_in[5];
  const float* w_ih_r  = (const float*)d_in[6];  // [3,2,256,128]
  const float* w_hh_r  = (const float*)d_in[7];  // [3,2,256,64]
  const float* b_r     = (const float*)d_in[8];  // [3,2,256]
  const float* w_attn  = (const float*)d_in[9];
  const float* g1  = (const float*)d_in[11];
  const float* be1 = (const float*)d_in[12];
  const float* m1  = (const float*)d_in[13];
  const float* v1  = (const float*)d_in[14];
  const float* w1  = (const float*)d_in[15];
  const float* b1  = (const float*)d_in[16];
  const float* w2  = (const float*)d_in[17];
  const float* b2  = (const float*)d_in[18];
  const float* g2  = (const float*)d_in[19];
  const float* be2 = (const float*)d_in[20];
  const float* m2  = (const float*)d_in[21];
  const float* v2  = (const float*)d_in[22];
  const float* w3  = (const float*)d_in[23];
  const float* b3  = (const float*)d_in[24];
  float* out = (float*)d_out;

  // ws layout: bufA [T,B,128] | bufB [T,B,128]  (in0 and pooled overlay dead regions)
  const size_t BUF_FLOATS = (size_t)T_LEN * BATCH * 128;
  float* bufA = (float*)d_ws;
  float* bufB = bufA + BUF_FLOATS;
  float* in0 = bufB;     // [T,B,64]; dead once layer1 writes bufB
  float* pooled = bufA;  // dead region after last layer reads bufA

  proj_kernel<<<T_LEN * BATCH / 4, 256, 0, stream>>>(x, w_proj, b_proj, in0);
  lstm_solo<64><<<256, 256, 0, stream>>>(in0, bufA, w_ih_l0, w_hh_l0, b_l0);
  lstm_solo<128><<<256, 256, 0, stream>>>(bufA, bufB, w_ih_r, w_hh_r, b_r);
  lstm_solo<128><<<256, 256, 0, stream>>>(bufB, bufA, w_ih_r + 65536, w_hh_r + 32768, b_r + 512);
  lstm_solo<128><<<256, 256, 0, stream>>>(bufA, bufB, w_ih_r + 131072, w_hh_r + 65536, b_r + 1024);
  attn_kernel<<<BATCH, 256, 0, stream>>>(bufB, w_attn, pooled);
  head_kernel<<<BATCH, 128, 0, stream>>>(pooled, g1, be1, m1, v1, w1, b1, w2, b2,
                                         g2, be2, m2, v2, w3, b3, out);
}